// Round 7
// baseline (419.645 us; speedup 1.0000x reference)
//
#include <hip/hip_runtime.h>

#define B_ 32
#define N_ 1009
#define C_ 768
#define H_ 12
#define D_ 64
#define M_ (B_*N_)          // 32288 tokens
#define MT_ 253             // ceil(M/128)
#define MPAD_ (MT_*128)     // 32384
#define NKV_ 1024           // padded sequence length for q/k/v storage
#define MT2_ 127            // ceil(M/256) for the 256-tile QKV GEMM

typedef __attribute__((ext_vector_type(4))) float f32x4;
typedef __attribute__((ext_vector_type(8))) short s16x8;

__device__ __forceinline__ unsigned short f2bf(float f) {
  union { float f; unsigned u; } x; x.f = f;
  unsigned r = x.u + 0x7fffu + ((x.u >> 16) & 1u);
  return (unsigned short)(r >> 16);
}

__device__ __forceinline__ f32x4 mfma16(s16x8 a, s16x8 b, f32x4 c) {
  return __builtin_amdgcn_mfma_f32_16x16x32_bf16(a, b, c, 0, 0, 0);
}

__device__ __forceinline__ void async16(const void* g, void* l) {
  __builtin_amdgcn_global_load_lds((const __attribute__((address_space(1))) void*)g,
                                   (__attribute__((address_space(3))) void*)l, 16, 0, 0);
}

__device__ __forceinline__ float exp2_fast(float x) {  // 2^x via v_exp_f32
  float r; asm("v_exp_f32 %0, %1" : "=v"(r) : "v"(x)); return r;
}

__device__ __forceinline__ unsigned cvt_pk_bf16(float lo, float hi) {
  unsigned r; asm("v_cvt_pk_bf16_f32 %0, %1, %2" : "=v"(r) : "v"(lo), "v"(hi)); return r;
}

// bijective XCD-chunk swizzle (m204): XCD x gets a contiguous range of work ids
template<int NWG>
__device__ __forceinline__ int xcd_swz(int bid) {
  constexpr int q = NWG >> 3, r = NWG & 7;
  const int x = bid & 7, l = bid >> 3;
  return (x < r ? x * (q + 1) : r * (q + 1) + (x - r) * q) + l;
}

// ---------------- x fp32 -> bf16 (pad rows zeroed) ----------------
__global__ void convert_x(const float* __restrict__ x, unsigned short* __restrict__ xb) {
  const long e = ((long)blockIdx.x * 256 + threadIdx.x) * 8;
  const long row = e / 768;
  s16x8 v;
  if (row < M_) {
#pragma unroll
    for (int j = 0; j < 8; ++j) v[j] = (short)f2bf(x[e + j]);
  } else {
    v = (s16x8){0,0,0,0,0,0,0,0};
  }
  *(s16x8*)&xb[e] = v;
}

// ---------------- W [R][C] fp32 -> W^T [C][R] bf16 ----------------
__global__ void transpose_convert(const float* __restrict__ in, unsigned short* __restrict__ out,
                                  int R, int Ccols) {
  __shared__ float tile[64][65];
  const int tc = blockIdx.x * 64, tr = blockIdx.y * 64;
#pragma unroll
  for (int i = 0; i < 16; ++i) {
    const int e = i * 256 + threadIdx.x;
    const int r = e >> 6, c = e & 63;
    tile[r][c] = in[(long)(tr + r) * Ccols + tc + c];
  }
  __syncthreads();
#pragma unroll
  for (int i = 0; i < 16; ++i) {
    const int e = i * 256 + threadIdx.x;
    const int c = e >> 6, r = e & 63;
    out[(long)(tc + c) * R + tr + r] = f2bf(tile[r][c]);
  }
}

// ---------------- zero the padding tokens 1009..1023 of K and V^T ----------------
__global__ void zero_pad(unsigned short* __restrict__ kb, unsigned short* __restrict__ vt) {
  const int t = blockIdx.x * 256 + threadIdx.x;
  if (t >= 368640) return;                       // 384*15*64 == 24576*15
  const int d = t & 63;
  const int r = t >> 6;                          // [0,5760)
  const int bh = r / 15, tok = 1009 + (r - bh * 15);
  kb[(((long)bh << 10) + tok) * 64 + d] = 0;     // K: [BH][1024][64]
  const int c = t % 15, row = t / 15;            // row < 24576
  vt[((long)row << 10) + 1009 + c] = 0;          // V^T: [BH*64 rows][1024]
}

// ---------------- QKV GEMM: 256x256 tile, BK=32, 512 thr / 8 waves, phase-scheduled ----
// 4 LDS K-tile slots (32KB each: A 16KB + B 16KB), slot = t&3, prefetch distance 3 tiles.
// Per K-tile: 2 phases x {ds_read frags || 2 global_load_lds -> barrier -> lgkmcnt(0) ->
// setprio(1) 16 MFMA setprio(0) -> barrier}; counted vmcnt(8) at group end (never 0
// mid-loop). Chunk swizzle ^((row>>1)&3) on both stage-source and read (proven r5/r6).
// Epilogue: q (prescaled 0.125*log2e) / k scatter [BH][1024][64]; V blocks (col0>=1536)
// transpose through LDS in two 128-token passes then write V^T [BH][64][1024] coalesced.
__global__ __launch_bounds__(512, 2)
void gemm_qkv(const unsigned short* __restrict__ A,
              const unsigned short* __restrict__ Bt,
              const float* __restrict__ bias,
              unsigned short* __restrict__ qo,
              unsigned short* __restrict__ ko,
              unsigned short* __restrict__ vo) {
  __shared__ __align__(16) unsigned short smem[65536];   // 128 KiB
  const int tid = threadIdx.x;
  const int lane = tid & 63;
  const int wv = tid >> 6;
  const int swzid = xcd_swz<MT2_ * 9>(blockIdx.x);
  const int bm = swzid / 9;
  const int bn = swzid - bm * 9;
  const int row0 = bm * 256;
  const int col0 = bn * 256;
  const int wr = (wv >> 2) * 128;    // wave M-offset (2 M-waves)
  const int wc = (wv & 3) * 64;      // wave N-offset (4 N-waves)
  const int l15 = lane & 15, g4 = lane >> 4;

  // per-thread staging source pointers (2 sweeps per operand), pre-swizzled chunk
  const unsigned short* pa[2];
  const unsigned short* pb[2];
#pragma unroll
  for (int s = 0; s < 2; ++s) {
    const int gg = s * 512 + tid;                 // 16B granule 0..1023
    const int row = gg >> 2;                      // 4 granules per 64B row
    const int ck = ((gg & 3) ^ ((row >> 1) & 3)) << 3;
    int rowA = row0 + row;
    if (rowA >= MPAD_) rowA -= 128;               // clamp last M-tile (data discarded later)
    pa[s] = A + (long)rowA * 768 + ck;
    pb[s] = Bt + (long)(col0 + row) * 768 + ck;
  }

  // stage operand `which` (0=A,1=B) of K-tile t into slot
  auto stage_op = [&](int slot, int koff, int which) {
#pragma unroll
    for (int s = 0; s < 2; ++s) {
      const int ldsb = slot * 32768 + which * 16384 + s * 8192 + wv * 1024;  // wave-uniform
      async16((which ? pb[s] : pa[s]) + koff, (char*)smem + ldsb);
    }
  };

  f32x4 acc[8][4] = {};

  // prologue: stage K-tiles 0,1,2 (12 loads/thread)
#pragma unroll
  for (int t0 = 0; t0 < 3; ++t0) {
    stage_op(t0, t0 * 32, 0);
    stage_op(t0, t0 * 32, 1);
  }
  asm volatile("s_waitcnt vmcnt(8)" ::: "memory");   // tile 0 landed; 1,2 in flight
  __builtin_amdgcn_s_barrier();

  for (int t = 0; t < 24; ++t) {
    const int sl = t & 3;
    const unsigned short* As = smem + sl * 16384;
    const unsigned short* Bs = As + 8192;
    const bool st = (t + 3) < 24;
    const int s3 = (t + 3) & 3;
    const int koff3 = (t + 3) * 32;

    // ---- phase A: frags m0-3 + all B; stage A(t+3) ----
    s16x8 af[4], bf[4];
#pragma unroll
    for (int m = 0; m < 4; ++m) {
      const int rA = wr + m * 16 + l15;
      af[m] = *(const s16x8*)&As[rA * 32 + ((g4 ^ ((rA >> 1) & 3)) << 3)];
    }
#pragma unroll
    for (int n = 0; n < 4; ++n) {
      const int rB = wc + n * 16 + l15;
      bf[n] = *(const s16x8*)&Bs[rB * 32 + ((g4 ^ ((rB >> 1) & 3)) << 3)];
    }
    if (st) stage_op(s3, koff3, 0);
    __builtin_amdgcn_s_barrier();
    asm volatile("s_waitcnt lgkmcnt(0)" ::: "memory");
    __builtin_amdgcn_s_setprio(1);
#pragma unroll
    for (int m = 0; m < 4; ++m)
#pragma unroll
      for (int n = 0; n < 4; ++n)
        acc[m][n] = mfma16(af[m], bf[n], acc[m][n]);
    __builtin_amdgcn_s_setprio(0);
    __builtin_amdgcn_s_barrier();

    // ---- phase B: frags m4-7 (B reused in regs); stage B(t+3) ----
#pragma unroll
    for (int m = 0; m < 4; ++m) {
      const int rA = wr + (m + 4) * 16 + l15;
      af[m] = *(const s16x8*)&As[rA * 32 + ((g4 ^ ((rA >> 1) & 3)) << 3)];
    }
    if (st) stage_op(s3, koff3, 1);
    __builtin_amdgcn_s_barrier();
    asm volatile("s_waitcnt lgkmcnt(0)" ::: "memory");
    __builtin_amdgcn_s_setprio(1);
#pragma unroll
    for (int m = 0; m < 4; ++m)
#pragma unroll
      for (int n = 0; n < 4; ++n)
        acc[m + 4][n] = mfma16(af[m], bf[n], acc[m + 4][n]);
    __builtin_amdgcn_s_setprio(0);

    // end-of-group counted wait: tile t+1 must be landed; keep newest 2 tiles in flight
    if (t <= 20)      asm volatile("s_waitcnt vmcnt(8)" ::: "memory");
    else if (t == 21) asm volatile("s_waitcnt vmcnt(4)" ::: "memory");
    else if (t == 22) asm volatile("s_waitcnt vmcnt(0)" ::: "memory");
    __builtin_amdgcn_s_barrier();
  }

  if (col0 >= 1536) {
    // ---- V path: two 128-token passes; transpose [256 d][128 tk] through LDS ----
    const int h0 = (col0 - 1536) >> 6;
    const int b0 = row0 / N_;
    const int split = (b0 + 1) * N_ - row0;   // tokens [0,split) belong to batch b0
#pragma unroll
    for (int pass = 0; pass < 2; ++pass) {
      __syncthreads();
      if ((wv >> 2) == pass) {               // waves owning this token half
#pragma unroll
        for (int m = 0; m < 8; ++m)
#pragma unroll
          for (int j = 0; j < 4; ++j)
#pragma unroll
            for (int n = 0; n < 4; ++n) {
              const int dl = wc + n * 16 + l15;
              const int tk = m * 16 + g4 * 4 + j;     // 0..127 local token
              smem[dl * 136 + tk] = f2bf(acc[m][n][j] + bias[col0 + dl]);
            }
      }
      __syncthreads();
      const int tb = pass * 128;
#pragma unroll
      for (int it = 0; it < 8; ++it) {
        const int gg2 = it * 512 + tid;
        const int dl = gg2 >> 4;
        const int t8 = (gg2 & 15) * 8;
        const s16x8 vv = *(const s16x8*)&smem[dl * 136 + t8];   // 16B aligned (272B rows)
        const int hh = h0 + (dl >> 6), dd = dl & 63;
#pragma unroll
        for (int jj = 0; jj < 8; ++jj) {
          const int tkb = tb + t8 + jj;
          const int grw = row0 + tkb;
          if (grw < M_) {
            const int bb = (tkb < split) ? b0 : b0 + 1;
            const int ntok = grw - bb * N_;
            vo[(((((long)bb * H_ + hh) << 6) + dd) << 10) + ntok] = (unsigned short)vv[jj];
          }
        }
      }
    }
    return;
  }

  // ---- q/k path (block-uniform: col0 multiples of 256, boundary at 768) ----
  const int which = col0 >= 768;
#pragma unroll
  for (int m = 0; m < 8; ++m) {
#pragma unroll
    for (int j = 0; j < 4; ++j) {
      const int grw = row0 + wr + m * 16 + g4 * 4 + j;
      if (grw < M_) {
        const int b = grw / N_;
        const int ntok = grw - b * N_;
#pragma unroll
        for (int n = 0; n < 4; ++n) {
          const int col = col0 + wc + n * 16 + l15;
          float val = acc[m][n][j] + bias[col];
          if (!which) val *= 0.18033688011112042f;  // 0.125 * log2(e): exp2-domain scores
          const int rem = col - which * 768;
          const int h = rem >> 6, d = rem & 63;
          const long bh2 = (long)b * H_ + h;
          (which ? ko : qo)[((bh2 << 10) + ntok) * 64 + d] = f2bf(val);
        }
      }
    }
  }
}

// ---------------- proj GEMM: A[M x 768] bf16, Bt[768 x 768] bf16, fp32 out + bias ------
// (round-6 structure: 128^2 tile, dbuf + counted vmcnt; measured ~50us, kept as-is)
__global__ __launch_bounds__(256, 4)
void gemm_proj(const unsigned short* __restrict__ A,
               const unsigned short* __restrict__ Bt,
               const float* __restrict__ bias,
               float* __restrict__ fo) {
  __shared__ __align__(16) unsigned short smem[17408];
  const int tid = threadIdx.x;
  const int lane = tid & 63;
  const int wv = tid >> 6;
  const int swzid = xcd_swz<MT_ * 6>(blockIdx.x);
  const int bm = swzid / 6;
  const int bn = swzid - bm * 6;
  const int row0 = bm * 128;
  const int col0 = bn * 128;
  const int wr = (wv >> 1) * 64;
  const int wc = (wv & 1) * 64;

  auto stage = [&](int bufsel, int kt) {
#pragma unroll
    for (int c = 0; c < 2; ++c) {
      const int lds_off = c * 4096 + wv * 1024;
      const int gg = c * 256 + wv * 64 + lane;
      const int row = gg >> 2;
      const int ck = ((gg & 3) ^ ((row >> 1) & 3)) << 3;
      async16(A + (long)(row0 + row) * 768 + kt + ck, (char*)smem + bufsel * 8192 + lds_off);
      async16(Bt + (long)(col0 + row) * 768 + kt + ck, (char*)smem + 16384 + bufsel * 8192 + lds_off);
    }
  };

  f32x4 acc[4][4] = {};
  stage(0, 0);
  for (int it = 0; it < 24; ++it) {
    const int buf = it & 1;
    if (it + 1 < 24) {
      stage(buf ^ 1, (it + 1) * 32);
      asm volatile("s_waitcnt vmcnt(4)" ::: "memory");
    } else {
      asm volatile("s_waitcnt vmcnt(0)" ::: "memory");
    }
    __builtin_amdgcn_s_barrier();

    const unsigned short* Asb = smem + buf * 4096;
    const unsigned short* Bsb = smem + 8192 + buf * 4096;
    s16x8 af[4], bfr[4];
#pragma unroll
    for (int m = 0; m < 4; ++m) {
      const int rA = wr + m * 16 + (lane & 15);
      af[m] = *(const s16x8*)&Asb[rA * 32 + (((lane >> 4) ^ ((rA >> 1) & 3)) << 3)];
    }
#pragma unroll
    for (int n = 0; n < 4; ++n) {
      const int rB = wc + n * 16 + (lane & 15);
      bfr[n] = *(const s16x8*)&Bsb[rB * 32 + (((lane >> 4) ^ ((rB >> 1) & 3)) << 3)];
    }
    __builtin_amdgcn_s_setprio(1);
#pragma unroll
    for (int m = 0; m < 4; ++m)
#pragma unroll
      for (int n = 0; n < 4; ++n)
        acc[m][n] = mfma16(af[m], bfr[n], acc[m][n]);
    __builtin_amdgcn_s_setprio(0);

    asm volatile("s_waitcnt lgkmcnt(0)" ::: "memory");
    __builtin_amdgcn_s_barrier();
  }

#pragma unroll
  for (int m = 0; m < 4; ++m) {
#pragma unroll
    for (int j = 0; j < 4; ++j) {
      const int grow = row0 + wr + m * 16 + (lane >> 4) * 4 + j;
      if (grow < M_) {
#pragma unroll
        for (int n = 0; n < 4; ++n) {
          const int col = col0 + wc + n * 16 + (lane & 15);
          fo[(long)grow * 768 + col] = acc[m][n][j] + bias[col];
        }
      }
    }
  }
}

// ---------------- prompt segment: out[n=0] = v[n=0] (V^T layout) ----------------
__global__ void misc_copy(const unsigned short* __restrict__ vt, unsigned short* __restrict__ og) {
  const int t = blockIdx.x * 256 + threadIdx.x;
  if (t >= B_ * H_ * D_) return;
  const int d = t & 63;
  const int bh = t >> 6;
  const int b = bh / H_, h = bh - b * H_;
  og[((long)b * N_) * 768 + h * 64 + d] = vt[(((long)bh << 6) + d) << 10];
}

// ---------------- flash attention: block = (b, h, 64-query tile), KVBLK=64 ----------------
// SWAPPED layout: QK^T computed as mfma(K,Q) -> S^T[key][q=lane&15]; PV as mfma(V^T,P)
// -> O^T[d][q=lane&15]. Softmax state (m,l) is one scalar per lane; reductions are
// in-lane over 16 regs + 2 shfl_xor(16,32). Q pre-scaled by 0.125*log2e -> exp2 domain.
__global__ __launch_bounds__(256, 4)
void attn_kernel(const unsigned short* __restrict__ qg,
                 const unsigned short* __restrict__ kg,
                 const unsigned short* __restrict__ vtg,
                 unsigned short* __restrict__ og) {
  __shared__ __align__(16) unsigned short Ks[2][64 * 64];
  __shared__ __align__(16) unsigned short Vts[2][64 * 64];
  __shared__ __align__(16) unsigned short Ps[64 * 64];

  const int bid = blockIdx.x;
  const int swz = (bid & 7) * 768 + (bid >> 3);
  const int tile = swz & 15;
  const int bh = swz >> 4;
  const int b = bh / H_;
  const int h = bh - b * H_;
  int qbase, qend, kstart, ktiles, kend;
  if (tile < 7) { qbase = 1 + 64 * tile;       qend = 433;  kstart = 1; ktiles = 7;  kend = 433; }
  else          { qbase = 433 + 64 * (tile-7); qend = 1009; kstart = 0; ktiles = 16; kend = 1009; }
  const long base  = (long)bh << 10;
  const long vbase = (long)bh << 6;
  const int tid = threadIdx.x, lane = tid & 63, wv = tid >> 6;
  const int q15 = lane & 15, q7 = lane & 7, g = lane >> 4;

  s16x8 qa[2];
  {
    const unsigned short* qp = qg + (base + qbase + wv * 16 + q15) * 64;
    qa[0] = *(const s16x8*)(qp + g * 8);
    qa[1] = *(const s16x8*)(qp + 32 + g * 8);
  }
  asm volatile("s_waitcnt vmcnt(0)" ::: "memory");

  f32x4 o[4] = {};
  float mrow = -1e30f, lrow = 0.f;

  auto stage = [&](int bufsel, int kb0) {
#pragma unroll
    for (int it = 0; it < 2; ++it) {
      const int ldsoff = (it * 256 + wv * 64) * 16;
      const int gr = it * 256 + wv * 64 + lane;
      const int rl = gr >> 3;
      const int cs = (gr & 7) ^ (rl & 7);
      async16(kg + ((base + kb0 + rl) << 6) + cs * 8, (char*)&Ks[bufsel][0] + ldsoff);
      async16(vtg + ((vbase + rl) << 10) + kb0 + cs * 8, (char*)&Vts[bufsel][0] + ldsoff);
    }
  };

  const int prow = wv * 16 + q15;

  stage(0, kstart);
  for (int kt = 0; kt < ktiles; ++kt) {
    const int buf = kt & 1;
    const int kbase0 = kstart + 64 * kt;
    if (kt + 1 < ktiles) {
      stage(buf ^ 1, kbase0 + 64);
      asm volatile("s_waitcnt vmcnt(4)" ::: "memory");
    } else {
      asm volatile("s_waitcnt vmcnt(0)" ::: "memory");
    }
    __builtin_amdgcn_s_barrier();

    f32x4 s4[4];
    __builtin_amdgcn_s_setprio(1);
#pragma unroll
    for (int n = 0; n < 4; ++n) {
      const int krow = n * 16 + q15;
      const int r7 = krow & 7;
      f32x4 a = {};
      a = mfma16(*(const s16x8*)&Ks[buf][krow * 64 + ((g ^ r7) << 3)],       qa[0], a);
      a = mfma16(*(const s16x8*)&Ks[buf][krow * 64 + (((4 + g) ^ r7) << 3)], qa[1], a);
      s4[n] = a;
    }
    __builtin_amdgcn_s_setprio(0);

    if (kbase0 + 64 > kend) {
#pragma unroll
      for (int n = 0; n < 4; ++n)
#pragma unroll
        for (int j = 0; j < 4; ++j)
          if (kbase0 + n * 16 + g * 4 + j >= kend) s4[n][j] = -1e30f;
    }

    float rmax = fmaxf(
        fmaxf(fmaxf(fmaxf(s4[0][0], s4[0][1]), fmaxf(s4[0][2], s4[0][3])),
              fmaxf(fmaxf(s4[1][0], s4[1][1]), fmaxf(s4[1][2], s4[1][3]))),
        fmaxf(fmaxf(fmaxf(s4[2][0], s4[2][1]), fmaxf(s4[2][2], s4[2][3])),
              fmaxf(fmaxf(s4[3][0], s4[3][1]), fmaxf(s4[3][2], s4[3][3]))));
    rmax = fmaxf(rmax, __shfl_xor(rmax, 16));
    rmax = fmaxf(rmax, __shfl_xor(rmax, 32));

    const float mnew = fmaxf(mrow, rmax);
    const float corr = exp2_fast(mrow - mnew);
    mrow = mnew;
#pragma unroll
    for (int f = 0; f < 4; ++f)
#pragma unroll
      for (int j = 0; j < 4; ++j) o[f][j] *= corr;

    float psum = 0.f;
#pragma unroll
    for (int n = 0; n < 4; ++n) {
#pragma unroll
      for (int j = 0; j < 4; ++j) {
        s4[n][j] = exp2_fast(s4[n][j] - mnew);
        psum += s4[n][j];
      }
      uint2 pw;
      pw.x = cvt_pk_bf16(s4[n][0], s4[n][1]);
      pw.y = cvt_pk_bf16(s4[n][2], s4[n][3]);
      *(uint2*)((char*)Ps + prow * 128 + (((n * 2 + (g >> 1)) ^ q7) << 4) + (g & 1) * 8) = pw;
    }
    psum += __shfl_xor(psum, 16);
    psum += __shfl_xor(psum, 32);
    lrow = lrow * corr + psum;

    s16x8 pa[2];
#pragma unroll
    for (int kf = 0; kf < 2; ++kf)
      pa[kf] = *(const s16x8*)((char*)Ps + prow * 128 + (((kf * 4 + g) ^ q7) << 4));
    __builtin_amdgcn_s_setprio(1);
#pragma unroll
    for (int f = 0; f < 4; ++f) {
      const int vrow = f * 16 + q15;
      const int v7 = vrow & 7;
#pragma unroll
      for (int kf = 0; kf < 2; ++kf) {
        const s16x8 vb = *(const s16x8*)&Vts[buf][vrow * 64 + (((kf * 4 + g) ^ v7) << 3)];
        o[f] = mfma16(vb, pa[kf], o[f]);
      }
    }
    __builtin_amdgcn_s_setprio(0);

    asm volatile("s_waitcnt lgkmcnt(0)" ::: "memory");
    __builtin_amdgcn_s_barrier();
  }

  const int qrow = qbase + wv * 16 + q15;
  if (qrow < qend) {
    const float inv = 1.0f / lrow;
    unsigned short* op = og + ((long)b * N_ + qrow) * 768 + h * 64 + g * 4;
#pragma unroll
    for (int f = 0; f < 4; ++f) {
      uint2 ow;
      ow.x = cvt_pk_bf16(o[f][0] * inv, o[f][1] * inv);
      ow.y = cvt_pk_bf16(o[f][2] * inv, o[f][3] * inv);
      *(uint2*)(op + f * 16) = ow;
    }
  }
}

extern "C" void kernel_launch(void* const* d_in, const int* in_sizes, int n_in,
                              void* d_out, int out_size, void* d_ws, size_t ws_size,
                              hipStream_t stream) {
  const float* x      = (const float*)d_in[0];
  const float* W_qkv  = (const float*)d_in[1];
  const float* b_qkv  = (const float*)d_in[2];
  const float* W_proj = (const float*)d_in[3];
  const float* b_proj = (const float*)d_in[4];
  float* out = (float*)d_out;

  unsigned short* ws = (unsigned short*)d_ws;
  unsigned short* wqkvT  = ws;                                  // [2304][768] bf16
  unsigned short* wprojT = wqkvT + (long)2304 * 768;            // [768][768] bf16
  unsigned short* qb = wprojT + (long)768 * 768;                // [B][H][1024][64] bf16
  const long kvsz = (long)B_ * H_ * NKV_ * D_;
  unsigned short* kb = qb + kvsz;                               // [B][H][1024][64] bf16
  unsigned short* vb = kb + kvsz;                               // V^T: [B][H][64][1024] bf16
  unsigned short* xb = vb + kvsz;                               // [MPAD][768] bf16
  unsigned short* attnout = xb;  // aliased: xb dead after QKV GEMM (stream-ordered)

  zero_pad<<<1440, 256, 0, stream>>>(kb, vb);
  convert_x<<<12144, 256, 0, stream>>>(x, xb);
  transpose_convert<<<dim3(2304 / 64, 768 / 64), 256, 0, stream>>>(W_qkv, wqkvT, 768, 2304);
  transpose_convert<<<dim3(768 / 64, 768 / 64), 256, 0, stream>>>(W_proj, wprojT, 768, 768);
  gemm_qkv<<<MT2_ * 9, 512, 0, stream>>>(xb, wqkvT, b_qkv, qb, kb, vb);
  misc_copy<<<96, 256, 0, stream>>>(vb, attnout);
  attn_kernel<<<B_ * H_ * 16, 256, 0, stream>>>(qb, kb, vb, attnout);
  gemm_proj<<<MT_ * 6, 256, 0, stream>>>(attnout, wprojT, b_proj, out);
}

// Round 8
// 405.168 us; speedup vs baseline: 1.0357x; 1.0357x over previous
//
#include <hip/hip_runtime.h>

#define B_ 32
#define N_ 1009
#define C_ 768
#define H_ 12
#define D_ 64
#define M_ (B_*N_)          // 32288 tokens
#define MT_ 253             // ceil(M/128)
#define MPAD_ (MT_*128)     // 32384
#define NKV_ 1024           // padded sequence length for q/k/v storage

typedef __attribute__((ext_vector_type(4))) float f32x4;
typedef __attribute__((ext_vector_type(8))) short s16x8;

__device__ __forceinline__ unsigned short f2bf(float f) {
  union { float f; unsigned u; } x; x.f = f;
  unsigned r = x.u + 0x7fffu + ((x.u >> 16) & 1u);
  return (unsigned short)(r >> 16);
}

__device__ __forceinline__ f32x4 mfma16(s16x8 a, s16x8 b, f32x4 c) {
  return __builtin_amdgcn_mfma_f32_16x16x32_bf16(a, b, c, 0, 0, 0);
}

__device__ __forceinline__ void async16(const void* g, void* l) {
  __builtin_amdgcn_global_load_lds((const __attribute__((address_space(1))) void*)g,
                                   (__attribute__((address_space(3))) void*)l, 16, 0, 0);
}

__device__ __forceinline__ float exp2_fast(float x) {  // 2^x via v_exp_f32
  float r; asm("v_exp_f32 %0, %1" : "=v"(r) : "v"(x)); return r;
}

__device__ __forceinline__ unsigned cvt_pk_bf16(float lo, float hi) {
  unsigned r; asm("v_cvt_pk_bf16_f32 %0, %1, %2" : "=v"(r) : "v"(lo), "v"(hi)); return r;
}

// bijective XCD-chunk swizzle (m204): XCD x gets a contiguous range of work ids
template<int NWG>
__device__ __forceinline__ int xcd_swz(int bid) {
  constexpr int q = NWG >> 3, r = NWG & 7;
  const int x = bid & 7, l = bid >> 3;
  return (x < r ? x * (q + 1) : r * (q + 1) + (x - r) * q) + l;
}

// ---------------- x fp32 -> bf16 (pad rows zeroed) ----------------
__global__ void convert_x(const float* __restrict__ x, unsigned short* __restrict__ xb) {
  const long e = ((long)blockIdx.x * 256 + threadIdx.x) * 8;
  const long row = e / 768;
  s16x8 v;
  if (row < M_) {
#pragma unroll
    for (int j = 0; j < 8; ++j) v[j] = (short)f2bf(x[e + j]);
  } else {
    v = (s16x8){0,0,0,0,0,0,0,0};
  }
  *(s16x8*)&xb[e] = v;
}

// ---------------- W [R][C] fp32 -> W^T [C][R] bf16 ----------------
__global__ void transpose_convert(const float* __restrict__ in, unsigned short* __restrict__ out,
                                  int R, int Ccols) {
  __shared__ float tile[64][65];
  const int tc = blockIdx.x * 64, tr = blockIdx.y * 64;
#pragma unroll
  for (int i = 0; i < 16; ++i) {
    const int e = i * 256 + threadIdx.x;
    const int r = e >> 6, c = e & 63;
    tile[r][c] = in[(long)(tr + r) * Ccols + tc + c];
  }
  __syncthreads();
#pragma unroll
  for (int i = 0; i < 16; ++i) {
    const int e = i * 256 + threadIdx.x;
    const int c = e >> 6, r = e & 63;
    out[(long)(tc + c) * R + tr + r] = f2bf(tile[r][c]);
  }
}

// ---------------- zero the padding tokens 1009..1023 of K and V^T ----------------
__global__ void zero_pad(unsigned short* __restrict__ kb, unsigned short* __restrict__ vt) {
  const int t = blockIdx.x * 256 + threadIdx.x;
  if (t >= 368640) return;                       // 384*15*64 == 24576*15
  const int d = t & 63;
  const int r = t >> 6;                          // [0,5760)
  const int bh = r / 15, tok = 1009 + (r - bh * 15);
  kb[(((long)bh << 10) + tok) * 64 + d] = 0;     // K: [BH][1024][64]
  const int c = t % 15, row = t / 15;            // row < 24576
  vt[((long)row << 10) + 1009 + c] = 0;          // V^T: [BH*64 rows][1024]
}

// ---------------- GEMM: A[M x 768] bf16 row-major, Bt[N x 768] bf16 (B^T) ----------------
// Grid: A-reuse-major (bm = swz/NBN) + bijective XCD chunking -> XCD working set L2-fits.
// K-loop: double-buffered LDS + counted vmcnt(4) + raw barriers (round-6 structure).
// LDS tiles XOR-swizzled (chunk ^= (row>>1)&3, pre-swizzled global src) -> 2-way-free reads.
// MODE 0 epilogue (NEW): q/k blocks stage acc -> LDS [tok][136] bf16 then write 16B
//   COALESCED vectors (dst d-offset multiple of 8 -> 16B aligned). q pre-scaled by
//   0.125*log2e. V blocks (col0>=1536) transpose through LDS, scalar stores (2B-align
//   constraint at batch splits). MODE 1: fp32 out + bias, direct.
template<int MODE>
__global__ __launch_bounds__(256, 4)
void gemm_bt(const unsigned short* __restrict__ A,
             const unsigned short* __restrict__ Bt,
             const float* __restrict__ bias,
             unsigned short* __restrict__ qo,
             unsigned short* __restrict__ ko,
             unsigned short* __restrict__ vo,
             float* __restrict__ fo) {
  // layout (bytes): As[0] @0, As[1] @8192, Bs[0] @16384, Bs[1] @24576; epilogue tile reuses all
  __shared__ __align__(16) unsigned short smem[17408];   // 34816 B -> 4 blocks/CU
  const int tid = threadIdx.x;
  const int lane = tid & 63;
  const int wv = tid >> 6;
  constexpr int NBN = (MODE == 0) ? 18 : 6;
  const int swzid = xcd_swz<MT_ * NBN>(blockIdx.x);
  const int bm = swzid / NBN;
  const int bn = swzid - bm * NBN;
  const int row0 = bm * 128;
  const int col0 = bn * 128;
  const int wr = (wv >> 1) * 64;
  const int wc = (wv & 1) * 64;

  // stage one 128x32 K-step of A and B into buffer bufsel (4 async16/thread)
  auto stage = [&](int bufsel, int kt) {
#pragma unroll
    for (int c = 0; c < 2; ++c) {
      const int lds_off = c * 4096 + wv * 1024;    // wave-uniform byte base within tile
      const int gg = c * 256 + wv * 64 + lane;     // this lane's 16B granule
      const int row = gg >> 2;                     // tile row (4 granules/row)
      const int ck = ((gg & 3) ^ ((row >> 1) & 3)) << 3;  // pre-swizzled source chunk
      async16(A + (long)(row0 + row) * 768 + kt + ck, (char*)smem + bufsel * 8192 + lds_off);
      async16(Bt + (long)(col0 + row) * 768 + kt + ck, (char*)smem + 16384 + bufsel * 8192 + lds_off);
    }
  };

  f32x4 acc[4][4] = {};
  stage(0, 0);
  for (int it = 0; it < 24; ++it) {
    const int buf = it & 1;
    if (it + 1 < 24) {
      stage(buf ^ 1, (it + 1) * 32);
      asm volatile("s_waitcnt vmcnt(4)" ::: "memory");   // current tile's 4 DMAs landed
    } else {
      asm volatile("s_waitcnt vmcnt(0)" ::: "memory");
    }
    __builtin_amdgcn_s_barrier();

    const unsigned short* Asb = smem + buf * 4096;          // shorts
    const unsigned short* Bsb = smem + 8192 + buf * 4096;
    s16x8 af[4], bfr[4];
#pragma unroll
    for (int m = 0; m < 4; ++m) {
      const int rA = wr + m * 16 + (lane & 15);
      af[m] = *(const s16x8*)&Asb[rA * 32 + (((lane >> 4) ^ ((rA >> 1) & 3)) << 3)];
    }
#pragma unroll
    for (int n = 0; n < 4; ++n) {
      const int rB = wc + n * 16 + (lane & 15);
      bfr[n] = *(const s16x8*)&Bsb[rB * 32 + (((lane >> 4) ^ ((rB >> 1) & 3)) << 3)];
    }
    __builtin_amdgcn_s_setprio(1);
#pragma unroll
    for (int m = 0; m < 4; ++m)
#pragma unroll
      for (int n = 0; n < 4; ++n)
        acc[m][n] = mfma16(af[m], bfr[n], acc[m][n]);
    __builtin_amdgcn_s_setprio(0);

    // drain our ds_reads before anyone overwrites this buffer next iteration
    asm volatile("s_waitcnt lgkmcnt(0)" ::: "memory");
    __builtin_amdgcn_s_barrier();
  }

  if (MODE == 0 && col0 < 1536) {
    // ---- q/k path (NEW): stage [tok 0..127][col 0..127] bf16 in LDS, then 16B stores ----
    const int qsel = col0 < 768;                 // whole block is q or k (col0 mult of 128)
#pragma unroll
    for (int m = 0; m < 4; ++m)
#pragma unroll
      for (int j = 0; j < 4; ++j)
#pragma unroll
        for (int n = 0; n < 4; ++n) {
          const int tk = wr + m * 16 + (lane >> 4) * 4 + j;
          const int cl = wc + n * 16 + (lane & 15);
          float val = acc[m][n][j] + bias[col0 + cl];
          if (qsel) val *= 0.18033688011112042f;  // 0.125 * log2(e): exp2-domain scores
          smem[tk * 136 + cl] = f2bf(val);
        }
    __syncthreads();
    unsigned short* const dst = qsel ? qo : ko;
    const int colb = col0 - (qsel ? 0 : 768);
#pragma unroll
    for (int it = 0; it < 8; ++it) {
      const int g = it * 256 + tid;
      const int tk = g >> 4;                     // local token
      const int ch = (g & 15) * 8;               // col chunk (8 shorts = 16B)
      const int grow = row0 + tk;
      if (grow < M_) {
        const s16x8 vv = *(const s16x8*)&smem[tk * 136 + ch];   // 16B aligned (272B rows)
        const int b = grow / N_;
        const int ntok = grow - b * N_;
        const int rem = colb + ch;
        const int h = rem >> 6, d = rem & 63;    // d multiple of 8 -> dest 16B aligned
        *(s16x8*)&dst[(((((long)b * H_ + h) << 10) + ntok) << 6) + d] = vv;
      }
    }
    return;
  }

  if (MODE == 0) {
    // ---- V path: stage transposed tile [d_local 0..127][tok 0..127] in LDS ----
#pragma unroll
    for (int m = 0; m < 4; ++m)
#pragma unroll
      for (int j = 0; j < 4; ++j)
#pragma unroll
        for (int n = 0; n < 4; ++n) {
          const int dl = wc + n * 16 + (lane & 15);
          const int tk = wr + m * 16 + (lane >> 4) * 4 + j;
          smem[dl * 136 + tk] = f2bf(acc[m][n][j] + bias[col0 + dl]);
        }
    __syncthreads();
    const int h0 = (col0 - 1536) >> 6;
    const int b0 = row0 / N_;
    const int split = (b0 + 1) * N_ - row0;   // block tokens [0,split) belong to batch b0
#pragma unroll
    for (int it = 0; it < 8; ++it) {
      const int g = it * 256 + tid;
      const int dl = g >> 4;
      const int t8 = (g & 15) * 8;
      const s16x8 vv = *(const s16x8*)&smem[dl * 136 + t8];   // 16B aligned
      const int hh = h0 + (dl >> 6), dd = dl & 63;
#pragma unroll
      for (int jj = 0; jj < 8; ++jj) {
        const int tkb = t8 + jj;
        const int grow = row0 + tkb;
        if (grow < M_) {
          const int bb = (tkb < split) ? b0 : b0 + 1;
          const int ntok = grow - bb * N_;
          vo[(((((long)bb * H_ + hh) << 6) + dd) << 10) + ntok] = (unsigned short)vv[jj];
        }
      }
    }
    return;
  }

  // ---- MODE 1: fp32 out + bias ----
#pragma unroll
  for (int m = 0; m < 4; ++m) {
#pragma unroll
    for (int j = 0; j < 4; ++j) {
      const int grow = row0 + wr + m * 16 + (lane >> 4) * 4 + j;
      if (grow < M_) {
#pragma unroll
        for (int n = 0; n < 4; ++n) {
          const int col = col0 + wc + n * 16 + (lane & 15);
          fo[(long)grow * 768 + col] = acc[m][n][j] + bias[col];
        }
      }
    }
  }
}

// ---------------- prompt segment: out[n=0] = v[n=0] (V^T layout) ----------------
__global__ void misc_copy(const unsigned short* __restrict__ vt, unsigned short* __restrict__ og) {
  const int t = blockIdx.x * 256 + threadIdx.x;
  if (t >= B_ * H_ * D_) return;
  const int d = t & 63;
  const int bh = t >> 6;
  const int b = bh / H_, h = bh - b * H_;
  og[((long)b * N_) * 768 + h * 64 + d] = vt[(((long)bh << 6) + d) << 10];
}

// ---------------- flash attention: block = (b, h, 64-query tile), KVBLK=64 ----------------
// SWAPPED layout: QK^T computed as mfma(K,Q) -> S^T[key][q=lane&15]; PV as mfma(V^T,P)
// -> O^T[d][q=lane&15]. Softmax state (m,l) is one scalar per lane; reductions are
// in-lane over 16 regs + 2 shfl_xor(16,32). Q pre-scaled by 0.125*log2e -> exp2 domain.
__global__ __launch_bounds__(256, 4)
void attn_kernel(const unsigned short* __restrict__ qg,
                 const unsigned short* __restrict__ kg,
                 const unsigned short* __restrict__ vtg,
                 unsigned short* __restrict__ og) {
  __shared__ __align__(16) unsigned short Ks[2][64 * 64];
  __shared__ __align__(16) unsigned short Vts[2][64 * 64];
  __shared__ __align__(16) unsigned short Ps[64 * 64];

  const int bid = blockIdx.x;
  const int swz = (bid & 7) * 768 + (bid >> 3);
  const int tile = swz & 15;
  const int bh = swz >> 4;
  const int b = bh / H_;
  const int h = bh - b * H_;
  int qbase, qend, kstart, ktiles, kend;
  if (tile < 7) { qbase = 1 + 64 * tile;       qend = 433;  kstart = 1; ktiles = 7;  kend = 433; }
  else          { qbase = 433 + 64 * (tile-7); qend = 1009; kstart = 0; ktiles = 16; kend = 1009; }
  const long base  = (long)bh << 10;
  const long vbase = (long)bh << 6;
  const int tid = threadIdx.x, lane = tid & 63, wv = tid >> 6;
  const int q15 = lane & 15, q7 = lane & 7, g = lane >> 4;

  s16x8 qa[2];
  {
    const unsigned short* qp = qg + (base + qbase + wv * 16 + q15) * 64;
    qa[0] = *(const s16x8*)(qp + g * 8);
    qa[1] = *(const s16x8*)(qp + 32 + g * 8);
  }
  asm volatile("s_waitcnt vmcnt(0)" ::: "memory");

  f32x4 o[4] = {};
  float mrow = -1e30f, lrow = 0.f;

  auto stage = [&](int bufsel, int kb0) {
#pragma unroll
    for (int it = 0; it < 2; ++it) {
      const int ldsoff = (it * 256 + wv * 64) * 16;
      const int gr = it * 256 + wv * 64 + lane;
      const int rl = gr >> 3;
      const int cs = (gr & 7) ^ (rl & 7);
      async16(kg + ((base + kb0 + rl) << 6) + cs * 8, (char*)&Ks[bufsel][0] + ldsoff);
      async16(vtg + ((vbase + rl) << 10) + kb0 + cs * 8, (char*)&Vts[bufsel][0] + ldsoff);
    }
  };

  const int prow = wv * 16 + q15;

  stage(0, kstart);
  for (int kt = 0; kt < ktiles; ++kt) {
    const int buf = kt & 1;
    const int kbase0 = kstart + 64 * kt;
    if (kt + 1 < ktiles) {
      stage(buf ^ 1, kbase0 + 64);
      asm volatile("s_waitcnt vmcnt(4)" ::: "memory");
    } else {
      asm volatile("s_waitcnt vmcnt(0)" ::: "memory");
    }
    __builtin_amdgcn_s_barrier();

    f32x4 s4[4];
    __builtin_amdgcn_s_setprio(1);
#pragma unroll
    for (int n = 0; n < 4; ++n) {
      const int krow = n * 16 + q15;
      const int r7 = krow & 7;
      f32x4 a = {};
      a = mfma16(*(const s16x8*)&Ks[buf][krow * 64 + ((g ^ r7) << 3)],       qa[0], a);
      a = mfma16(*(const s16x8*)&Ks[buf][krow * 64 + (((4 + g) ^ r7) << 3)], qa[1], a);
      s4[n] = a;
    }
    __builtin_amdgcn_s_setprio(0);

    if (kbase0 + 64 > kend) {
#pragma unroll
      for (int n = 0; n < 4; ++n)
#pragma unroll
        for (int j = 0; j < 4; ++j)
          if (kbase0 + n * 16 + g * 4 + j >= kend) s4[n][j] = -1e30f;
    }

    float rmax = fmaxf(
        fmaxf(fmaxf(fmaxf(s4[0][0], s4[0][1]), fmaxf(s4[0][2], s4[0][3])),
              fmaxf(fmaxf(s4[1][0], s4[1][1]), fmaxf(s4[1][2], s4[1][3]))),
        fmaxf(fmaxf(fmaxf(s4[2][0], s4[2][1]), fmaxf(s4[2][2], s4[2][3])),
              fmaxf(fmaxf(s4[3][0], s4[3][1]), fmaxf(s4[3][2], s4[3][3]))));
    rmax = fmaxf(rmax, __shfl_xor(rmax, 16));
    rmax = fmaxf(rmax, __shfl_xor(rmax, 32));

    const float mnew = fmaxf(mrow, rmax);
    const float corr = exp2_fast(mrow - mnew);
    mrow = mnew;
#pragma unroll
    for (int f = 0; f < 4; ++f)
#pragma unroll
      for (int j = 0; j < 4; ++j) o[f][j] *= corr;

    float psum = 0.f;
#pragma unroll
    for (int n = 0; n < 4; ++n) {
#pragma unroll
      for (int j = 0; j < 4; ++j) {
        s4[n][j] = exp2_fast(s4[n][j] - mnew);
        psum += s4[n][j];
      }
      uint2 pw;
      pw.x = cvt_pk_bf16(s4[n][0], s4[n][1]);
      pw.y = cvt_pk_bf16(s4[n][2], s4[n][3]);
      *(uint2*)((char*)Ps + prow * 128 + (((n * 2 + (g >> 1)) ^ q7) << 4) + (g & 1) * 8) = pw;
    }
    psum += __shfl_xor(psum, 16);
    psum += __shfl_xor(psum, 32);
    lrow = lrow * corr + psum;

    s16x8 pa[2];
#pragma unroll
    for (int kf = 0; kf < 2; ++kf)
      pa[kf] = *(const s16x8*)((char*)Ps + prow * 128 + (((kf * 4 + g) ^ q7) << 4));
    __builtin_amdgcn_s_setprio(1);
#pragma unroll
    for (int f = 0; f < 4; ++f) {
      const int vrow = f * 16 + q15;
      const int v7 = vrow & 7;
#pragma unroll
      for (int kf = 0; kf < 2; ++kf) {
        const s16x8 vb = *(const s16x8*)&Vts[buf][vrow * 64 + (((kf * 4 + g) ^ v7) << 3)];
        o[f] = mfma16(vb, pa[kf], o[f]);
      }
    }
    __builtin_amdgcn_s_setprio(0);

    asm volatile("s_waitcnt lgkmcnt(0)" ::: "memory");
    __builtin_amdgcn_s_barrier();
  }

  const int qrow = qbase + wv * 16 + q15;
  if (qrow < qend) {
    const float inv = 1.0f / lrow;
    unsigned short* op = og + ((long)b * N_ + qrow) * 768 + h * 64 + g * 4;
#pragma unroll
    for (int f = 0; f < 4; ++f) {
      uint2 ow;
      ow.x = cvt_pk_bf16(o[f][0] * inv, o[f][1] * inv);
      ow.y = cvt_pk_bf16(o[f][2] * inv, o[f][3] * inv);
      *(uint2*)(op + f * 16) = ow;
    }
  }
}

extern "C" void kernel_launch(void* const* d_in, const int* in_sizes, int n_in,
                              void* d_out, int out_size, void* d_ws, size_t ws_size,
                              hipStream_t stream) {
  const float* x      = (const float*)d_in[0];
  const float* W_qkv  = (const float*)d_in[1];
  const float* b_qkv  = (const float*)d_in[2];
  const float* W_proj = (const float*)d_in[3];
  const float* b_proj = (const float*)d_in[4];
  float* out = (float*)d_out;

  unsigned short* ws = (unsigned short*)d_ws;
  unsigned short* wqkvT  = ws;                                  // [2304][768] bf16
  unsigned short* wprojT = wqkvT + (long)2304 * 768;            // [768][768] bf16
  unsigned short* qb = wprojT + (long)768 * 768;                // [B][H][1024][64] bf16
  const long kvsz = (long)B_ * H_ * NKV_ * D_;
  unsigned short* kb = qb + kvsz;                               // [B][H][1024][64] bf16
  unsigned short* vb = kb + kvsz;                               // V^T: [B][H][64][1024] bf16
  unsigned short* xb = vb + kvsz;                               // [MPAD][768] bf16
  unsigned short* attnout = xb;  // aliased: xb dead after QKV GEMM (stream-ordered)

  zero_pad<<<1440, 256, 0, stream>>>(kb, vb);
  convert_x<<<12144, 256, 0, stream>>>(x, xb);
  transpose_convert<<<dim3(2304 / 64, 768 / 64), 256, 0, stream>>>(W_qkv, wqkvT, 768, 2304);
  transpose_convert<<<dim3(768 / 64, 768 / 64), 256, 0, stream>>>(W_proj, wprojT, 768, 768);
  gemm_bt<0><<<MT_ * 18, 256, 0, stream>>>(xb, wqkvT, b_qkv, qb, kb, vb, nullptr);
  misc_copy<<<96, 256, 0, stream>>>(vb, attnout);
  attn_kernel<<<B_ * H_ * 16, 256, 0, stream>>>(qb, kb, vb, attnout);
  gemm_bt<1><<<MT_ * 6, 256, 0, stream>>>(attnout, wprojT, b_proj, nullptr, nullptr, nullptr, out);
}